// Round 1
// 764.197 us; speedup vs baseline: 1.0518x; 1.0518x over previous
//
#include <hip/hip_runtime.h>
#include <hip/hip_bf16.h>
#include <cstdint>
#include <cstddef>

typedef __hip_bfloat16 bf16;
typedef __attribute__((ext_vector_type(8))) short short8;
typedef __attribute__((ext_vector_type(4))) float floatx4;

#define Bsz 16
#define Lseq 4096
#define Hd 256
#define NM 32          // complex modes per channel
#define NMH 16         // modes per lane after 2-way split
#define NCH 16         // chunks
#define TCH 256        // chunk length (NCH*TCH == Lseq)
#define Mtot (Bsz*Lseq)
#define CSTRIDE (2*NM*Hd)   // 16384 floats per component plane

__device__ __forceinline__ float gelu_tanh(float y) {
  // 0.5*y*(1+tanh(0.79788456*(y+0.044715*y^3))) == y*sigmoid(1.5957691*(y+0.044715*y^3))
  float y2 = y * y;
  float q = fmaf(0.044715f, y2, 1.0f);
  float a = 1.5957691216057308f * y * q;
  float e = __expf(-a);
  return y * __frcp_rn(1.0f + e);
}

// ---------------- K0: per-(dir,d,n) constants ----------------
// cst planes: 0=wr 1=wi 2=Cr 3=Ci 4=wTr 5=wTi ; idx = dir*8192 + n*256 + d
__global__ __launch_bounds__(256) void k_const(
    const float* __restrict__ ldt_fw, const float* __restrict__ lar_fw,
    const float* __restrict__ ai_fw,  const float* __restrict__ C_fw,
    const float* __restrict__ ldt_bw, const float* __restrict__ lar_bw,
    const float* __restrict__ ai_bw,  const float* __restrict__ C_bw,
    float* __restrict__ cst) {
  int t = blockIdx.x * 256 + threadIdx.x;       // 16384 total
  int d = t & 255, n = (t >> 8) & 31, dir = t >> 13;
  const float* ldt = dir ? ldt_bw : ldt_fw;
  const float* lar = dir ? lar_bw : lar_fw;
  const float* ai  = dir ? ai_bw  : ai_fw;
  const float* C   = dir ? C_bw   : C_fw;

  float dt = expf(ldt[d]);
  float Ar = -expf(lar[d * NM + n]);
  float Ai = ai[d * NM + n];
  float cr = C[(d * NM + n) * 2 + 0];
  float ci = C[(d * NM + n) * 2 + 1];

  float er = expf(Ar * dt);
  float sn, cs;
  sincosf(Ai * dt, &sn, &cs);
  float wr = er * cs, wi = er * sn;
  // Ceff = 2*Cc*(w-1)/(A+1e-8)
  float nr = wr - 1.f, ni = wi;
  float tr = cr * nr - ci * ni;
  float ti = cr * ni + ci * nr;
  float dr = Ar + 1e-8f, di = Ai;
  float inv = 1.f / (dr * dr + di * di);
  float Cr = 2.f * (tr * dr + ti * di) * inv;
  float Ci = 2.f * (ti * dr - tr * di) * inv;
  // wT = w^TCH
  float erT = expf((float)TCH * Ar * dt);
  float snT, csT;
  sincosf((float)TCH * Ai * dt, &snT, &csT);
  float wTr = erT * csT, wTi = erT * snT;

  int base = dir * (NM * Hd) + n * Hd + d;
  cst[0 * CSTRIDE + base] = wr;
  cst[1 * CSTRIDE + base] = wi;
  cst[2 * CSTRIDE + base] = Cr;
  cst[3 * CSTRIDE + base] = Ci;
  cst[4 * CSTRIDE + base] = wTr;
  cst[5 * CSTRIDE + base] = wTi;
}

// ---------------- K0b: conv_w fp32 -> bf16 ----------------
__global__ __launch_bounds__(256) void k_wconv(
    const float* __restrict__ W, bf16* __restrict__ Wb, int n) {
  int i = blockIdx.x * 256 + threadIdx.x;
  if (i < n) Wb[i] = __float2bfloat16(W[i]);
}

// ---------------- K1: chunk-local end states ----------------
// 512 threads: d = tid>>1, h = tid&1 owns modes [h*16, h*16+16).
// Sloc layout: [b][dir][c][n2(64)][d]  (n2 = 2n for re, 2n+1 for im)
__global__ __launch_bounds__(512, 4) void k_scan1(
    const float* __restrict__ x, const float* __restrict__ cst,
    float* __restrict__ Sloc) {
  const int c = blockIdx.x, b = blockIdx.y, dir = blockIdx.z;
  const int d = threadIdx.x >> 1, h = threadIdx.x & 1;
  const int nbase = h * NMH;
  float wr[NMH], wi[NMH], sr[NMH], si[NMH];
  const float* cw = cst + dir * (NM * Hd) + d;
#pragma unroll
  for (int n = 0; n < NMH; ++n) {
    wr[n] = cw[(nbase + n) * Hd];
    wi[n] = cw[CSTRIDE + (nbase + n) * Hd];
    sr[n] = 0.f; si[n] = 0.f;
  }
  const int l0 = c * TCH;
  const float* xp = x + (size_t)b * Lseq * Hd + d;
  const int stp = dir ? -Hd : Hd;
  int pos = dir ? (Lseq - 1 - l0) : l0;
  const float* px = xp + (size_t)pos * Hd;
  float ua = px[0]; px += stp;
  float ub = px[0]; px += stp;
#pragma unroll 1
  for (int t = 0; t < TCH; ++t) {
    float unew = 0.f;
    if (t + 2 < TCH) unew = px[0];
    px += stp;
    float u = ua;
#pragma unroll
    for (int n = 0; n < NMH; ++n) {
      float t0  = fmaf(wr[n], sr[n], u);
      float nsi = wr[n] * si[n];
      nsi = fmaf(wi[n], sr[n], nsi);
      sr[n] = fmaf(-wi[n], si[n], t0);
      si[n] = nsi;
    }
    ua = ub; ub = unew;
  }
  float* outp = Sloc + (((size_t)(b * 2 + dir) * NCH + c) * 64) * Hd + d;
#pragma unroll
  for (int n = 0; n < NMH; ++n) {
    outp[(2 * (nbase + n)) * Hd]     = sr[n];
    outp[(2 * (nbase + n) + 1) * Hd] = si[n];
  }
}

// ---------------- K2: cross-chunk prefix (in-place on Sloc) ----------------
__global__ __launch_bounds__(256) void k_scan2(
    const float* __restrict__ cst, float* __restrict__ S) {
  const int b = blockIdx.x, dir = blockIdx.y, d = threadIdx.x;
  float wTr[NM], wTi[NM], sr[NM], si[NM];
  const float* cw = cst + dir * (NM * Hd) + d;
#pragma unroll
  for (int n = 0; n < NM; ++n) {
    wTr[n] = cw[4 * CSTRIDE + n * Hd];
    wTi[n] = cw[5 * CSTRIDE + n * Hd];
    sr[n] = 0.f; si[n] = 0.f;
  }
  for (int c = 0; c < NCH; ++c) {
    size_t off = (((size_t)(b * 2 + dir) * NCH + c) * 64) * Hd + d;
    float* p = S + off;
#pragma unroll
    for (int n = 0; n < NM; ++n) {
      float lr = p[(2 * n) * Hd], li = p[(2 * n + 1) * Hd];  // read local
      p[(2 * n) * Hd]     = sr[n];                            // write prefix
      p[(2 * n + 1) * Hd] = si[n];
      float t0  = fmaf(wTr[n], sr[n], lr);
      float nsr = fmaf(-wTi[n], si[n], t0);
      float nsi = fmaf(wTr[n], si[n], li);
      nsi = fmaf(wTi[n], sr[n], nsi);
      sr[n] = nsr; si[n] = nsi;
    }
  }
}

// ---------------- K3: final scan + Dskip + GELU -> Act (bf16) ----------------
// 512 threads: d = tid>>1, h = tid&1 owns modes [h*16, h*16+16).
// Partial output projections combined via shfl_xor(1); both lanes store the
// (identical) value — same-address same-value store is deterministic and
// avoids per-iteration exec masking.
// Act layout: [m = b*L + l][ch] with ch = dir*256 + d, 512 channels
__global__ __launch_bounds__(512, 4) void k_scan3(
    const float* __restrict__ x, const float* __restrict__ cst,
    const float* __restrict__ Sstart, const float* __restrict__ Dskip,
    bf16* __restrict__ Act) {
  const int c = blockIdx.x, b = blockIdx.y, dir = blockIdx.z;
  const int d = threadIdx.x >> 1, h = threadIdx.x & 1;
  const int nbase = h * NMH;
  float wr[NMH], wi[NMH], cr[NMH], ci[NMH], sr[NMH], si[NMH];
  const float* cw = cst + dir * (NM * Hd) + d;
#pragma unroll
  for (int n = 0; n < NMH; ++n) {
    wr[n] = cw[(nbase + n) * Hd];
    wi[n] = cw[CSTRIDE + (nbase + n) * Hd];
    cr[n] = cw[2 * CSTRIDE + (nbase + n) * Hd];
    ci[n] = cw[3 * CSTRIDE + (nbase + n) * Hd];
  }
  const float* sp = Sstart + (((size_t)(b * 2 + dir) * NCH + c) * 64) * Hd + d;
#pragma unroll
  for (int n = 0; n < NMH; ++n) {
    sr[n] = sp[(2 * (nbase + n)) * Hd];
    si[n] = sp[(2 * (nbase + n) + 1) * Hd];
  }
  const float Dk = Dskip[d];
  const int l0 = c * TCH;
  const float* xp = x + (size_t)b * Lseq * Hd + d;
  const int stp = dir ? -Hd : Hd;
  int pos0 = dir ? (Lseq - 1 - l0) : l0;
  const float* px = xp + (size_t)pos0 * Hd;
  float ua = px[0]; px += stp;
  float ub = px[0]; px += stp;
  bf16* apw = Act + (size_t)b * Lseq * 512 + (size_t)pos0 * 512 + dir * 256 + d;
  const ptrdiff_t astp = dir ? -512 : 512;
#pragma unroll 1
  for (int t = 0; t < TCH; ++t) {
    float unew = 0.f;
    if (t + 2 < TCH) unew = px[0];
    px += stp;
    float u = ua;
    float yp = 0.f;
#pragma unroll
    for (int n = 0; n < NMH; ++n) {
      float t0  = fmaf(wr[n], sr[n], u);
      float nsi = wr[n] * si[n];
      nsi = fmaf(wi[n], sr[n], nsi);
      sr[n] = fmaf(-wi[n], si[n], t0);
      si[n] = nsi;
      yp = fmaf(cr[n], sr[n], yp);
      yp = fmaf(-ci[n], si[n], yp);
    }
    float tot = yp + __shfl_xor(yp, 1);
    float y = fmaf(u, Dk, tot);
    float ge = gelu_tanh(y);
    *apw = __float2bfloat16(ge);
    apw += astp;
    ua = ub; ub = unew;
  }
}

// ---------------- K4: GEMM (M,K=512)x(1024,K) + bias + GLU -> z (fp32, into d_out) ----------------
#define LDK 40  // padded LDS stride in shorts (32 + 8, keeps 16B alignment)
__global__ __launch_bounds__(256) void k_gemm(
    const bf16* __restrict__ Act, const bf16* __restrict__ W,
    const float* __restrict__ bias, float* __restrict__ z) {
  __shared__ __align__(16) short As[128 * LDK];
  __shared__ __align__(16) short Bas[128 * LDK];
  __shared__ __align__(16) short Bgs[128 * LDK];
  const int bi = blockIdx.x, bj = blockIdx.y;
  const int tid = threadIdx.x, lane = tid & 63, wv = tid >> 6;
  const int wm = (wv & 1) * 64, wn = (wv >> 1) * 64;
  const int M0 = bi * 128;
  floatx4 acc_a[4][4], acc_g[4][4];
#pragma unroll
  for (int i = 0; i < 4; ++i)
#pragma unroll
    for (int j = 0; j < 4; ++j) {
      acc_a[i][j] = (floatx4){0.f, 0.f, 0.f, 0.f};
      acc_g[i][j] = (floatx4){0.f, 0.f, 0.f, 0.f};
    }
  const int row2 = tid >> 2;        // 0..63
  const int kc = (tid & 3) * 8;     // 0,8,16,24 (elements)
  const int fr = lane & 15, fk = (lane >> 4) * 8;

  for (int kb = 0; kb < 512; kb += 32) {
#pragma unroll
    for (int r = 0; r < 2; ++r) {
      int rr = row2 + r * 64;
      *(int4*)&As[rr * LDK + kc]  = *(const int4*)&Act[(size_t)(M0 + rr) * 512 + kb + kc];
      *(int4*)&Bas[rr * LDK + kc] = *(const int4*)&W[(size_t)(bj * 128 + rr) * 512 + kb + kc];
      *(int4*)&Bgs[rr * LDK + kc] = *(const int4*)&W[(size_t)(512 + bj * 128 + rr) * 512 + kb + kc];
    }
    __syncthreads();
    short8 af[4], bfa[4], bfg[4];
#pragma unroll
    for (int i = 0; i < 4; ++i) af[i]  = *(const short8*)&As[(wm + 16 * i + fr) * LDK + fk];
#pragma unroll
    for (int j = 0; j < 4; ++j) bfa[j] = *(const short8*)&Bas[(wn + 16 * j + fr) * LDK + fk];
#pragma unroll
    for (int j = 0; j < 4; ++j) bfg[j] = *(const short8*)&Bgs[(wn + 16 * j + fr) * LDK + fk];
#pragma unroll
    for (int i = 0; i < 4; ++i)
#pragma unroll
      for (int j = 0; j < 4; ++j) {
        acc_a[i][j] = __builtin_amdgcn_mfma_f32_16x16x32_bf16(af[i], bfa[j], acc_a[i][j], 0, 0, 0);
        acc_g[i][j] = __builtin_amdgcn_mfma_f32_16x16x32_bf16(af[i], bfg[j], acc_g[i][j], 0, 0, 0);
      }
    __syncthreads();
  }
  // epilogue: bias + GLU, write z[m][o] fp32, o in [0,512)
  const int col = lane & 15, rquad = (lane >> 4) * 4;
#pragma unroll
  for (int j = 0; j < 4; ++j) {
    int o = bj * 128 + wn + 16 * j + col;
    float ba = bias[o];
    float bg = bias[512 + o];
#pragma unroll
    for (int i = 0; i < 4; ++i) {
      int mbase = M0 + wm + 16 * i + rquad;
#pragma unroll
      for (int rg = 0; rg < 4; ++rg) {
        float a = acc_a[i][j][rg] + ba;
        float g = acc_g[i][j][rg] + bg;
        float zv = a * __frcp_rn(1.f + __expf(-g));
        z[(size_t)(mbase + rg) * 512 + o] = zv;
      }
    }
  }
}

// ---------------- K5: LayerNorm over 512 (in-place on d_out, fp32) ----------------
__global__ __launch_bounds__(256) void k_ln(
    float* __restrict__ z, const float* __restrict__ gamma,
    const float* __restrict__ beta) {
  const int m = blockIdx.x * 4 + (threadIdx.x >> 6);
  const int lane = threadIdx.x & 63;
  float* zp = z + (size_t)m * 512;
  float v[8], s = 0.f, sq = 0.f;
#pragma unroll
  for (int j = 0; j < 8; ++j) {
    v[j] = zp[j * 64 + lane];
    s += v[j];
    sq = fmaf(v[j], v[j], sq);
  }
#pragma unroll
  for (int off = 32; off > 0; off >>= 1) {
    s += __shfl_xor(s, off);
    sq += __shfl_xor(sq, off);
  }
  float mean = s * (1.f / 512.f);
  float var = fmaf(-mean, mean, sq * (1.f / 512.f));
  float inv = rsqrtf(var + 1e-5f);
#pragma unroll
  for (int j = 0; j < 8; ++j) {
    int cidx = j * 64 + lane;
    float g = gamma[cidx], be = beta[cidx];
    zp[cidx] = fmaf((v[j] - mean) * inv, g, be);
  }
}

extern "C" void kernel_launch(void* const* d_in, const int* in_sizes, int n_in,
                              void* d_out, int out_size, void* d_ws, size_t ws_size,
                              hipStream_t stream) {
  const float* x      = (const float*)d_in[0];
  const float* ldt_fw = (const float*)d_in[1];
  const float* lar_fw = (const float*)d_in[2];
  const float* ai_fw  = (const float*)d_in[3];
  const float* C_fw   = (const float*)d_in[4];
  const float* ldt_bw = (const float*)d_in[5];
  const float* lar_bw = (const float*)d_in[6];
  const float* ai_bw  = (const float*)d_in[7];
  const float* C_bw   = (const float*)d_in[8];
  const float* Dskip  = (const float*)d_in[9];
  const float* W      = (const float*)d_in[10];
  const float* bias   = (const float*)d_in[11];
  const float* gamma  = (const float*)d_in[12];
  const float* beta   = (const float*)d_in[13];
  float* out = (float*)d_out;

  char* wsb = (char*)d_ws;
  float* cst  = (float*)wsb;                       // 393,216 B (pad to 512K)
  bf16*  Wb   = (bf16*)(wsb + 524288);             // 1,048,576 B
  float* Sloc = (float*)(wsb + 524288 + 1048576);  // 33,554,432 B
  bf16*  Act  = (bf16*)(wsb + 524288 + 1048576 + 33554432u); // 67,108,864 B
  // total ws: ~102 MB

  k_const<<<dim3(64), dim3(256), 0, stream>>>(ldt_fw, lar_fw, ai_fw, C_fw,
                                              ldt_bw, lar_bw, ai_bw, C_bw, cst);
  k_wconv<<<dim3(2048), dim3(256), 0, stream>>>(W, Wb, 1024 * 512);
  k_scan1<<<dim3(NCH, Bsz, 2), dim3(512), 0, stream>>>(x, cst, Sloc);
  k_scan2<<<dim3(Bsz, 2), dim3(256), 0, stream>>>(cst, Sloc);
  k_scan3<<<dim3(NCH, Bsz, 2), dim3(512), 0, stream>>>(x, cst, Sloc, Dskip, Act);
  k_gemm<<<dim3(Mtot / 128, 4), dim3(256), 0, stream>>>(Act, Wb, bias, out);
  k_ln<<<dim3(Mtot / 4), dim3(256), 0, stream>>>(out, gamma, beta);
}